// Round 1
// baseline (1497.226 us; speedup 1.0000x reference)
//
#include <hip/hip_runtime.h>
#include <hip/hip_bf16.h>

#define HSTEP 0.1f
#define LN_EPS 1e-5f

typedef short short8 __attribute__((ext_vector_type(8)));
typedef float f32x4 __attribute__((ext_vector_type(4)));

__device__ __forceinline__ unsigned short f2bf(float f) {
  unsigned u = __builtin_bit_cast(unsigned, f);
  u += 0x7FFFu + ((u >> 16) & 1u);
  return (unsigned short)(u >> 16);
}
__device__ __forceinline__ float bf2f(unsigned short s) {
  unsigned u = ((unsigned)s) << 16;
  return __builtin_bit_cast(float, u);
}

// ---- weights fp32 -> bf16 ----
__global__ __launch_bounds__(256) void k_cvt(const float* __restrict__ s,
                                             unsigned short* __restrict__ d, int n) {
  int i = blockIdx.x * 256 + threadIdx.x;
  if (i < n) d[i] = f2bf(s[i]);
}

// ---- tiled transpose: src (R x C) -> dst (C x R) ----
__global__ __launch_bounds__(256) void k_transpose(const float* __restrict__ src,
                                                   float* __restrict__ dst, int R, int C) {
  __shared__ float tile[64][65];
  long long c0 = (long long)blockIdx.x * 64;
  long long r0 = (long long)blockIdx.y * 64;
  int t = threadIdx.x;
  int tc = t & 63, tr = t >> 6;
  for (int p = 0; p < 16; ++p) {
    int rl = tr + p * 4;
    long long r = r0 + rl, c = c0 + tc;
    if (r < R && c < C) tile[rl][tc] = src[r * C + c];
  }
  __syncthreads();
  for (int p = 0; p < 16; ++p) {
    int cl = tr + p * 4;
    long long c = c0 + cl, r = r0 + tc;
    if (c < C && r < R) dst[c * R + r] = tile[tc][cl];
  }
}

__device__ __forceinline__ void stats_reduce(float ssum, float ssq, double* sOut) {
  for (int off = 32; off; off >>= 1) {
    ssum += __shfl_down(ssum, off);
    ssq  += __shfl_down(ssq, off);
  }
  __shared__ float rs[4], rq[4];
  int t = threadIdx.x;
  if ((t & 63) == 0) { rs[t >> 6] = ssum; rq[t >> 6] = ssq; }
  __syncthreads();
  if (t == 0) {
    atomicAdd(sOut + 0, (double)(rs[0] + rs[1] + rs[2] + rs[3]));
    atomicAdd(sOut + 1, (double)(rq[0] + rq[1] + rq[2] + rq[3]));
  }
}

__device__ __forceinline__ void ln_params(const double* sIn, long long cnt, float& mu, float& rs) {
  float cf = (float)cnt;
  float m = (float)sIn[0] / cf;
  float q = (float)sIn[1] / cf;
  mu = m;
  rs = rsqrtf(fmaxf(q - m * m, 0.f) + LN_EPS);
}

// ---- generic 64x64 apply: Y = K @ pre(X), per 64-item group ----
// PRE: 0 none, 1 relu(ln(x)) using sIn
// OUT_MODE: 0 bf16 row-major Yb, 1 Yf += H*acc (fp32 row-major), 2 fp32 channel-major Yf (ld=ldC), 3 fp32 row-major Yf
template<int PRE, int STATS, int OUT_MODE, typename TIN>
__global__ __launch_bounds__(256) void k_mv64(
    const TIN* __restrict__ X, const unsigned short* __restrict__ Kb,
    unsigned short* __restrict__ Yb, float* __restrict__ Yf,
    int W, long long cnt, const double* __restrict__ sIn, double* __restrict__ sOut, int ldC) {
  int t = threadIdx.x;
  int wave = t >> 6, lane = t & 63;
  int g0 = blockIdx.x * 64;
  float mu = 0.f, rs = 1.f;
  if constexpr (PRE) ln_params(sIn, cnt, mu, rs);
  __shared__ __align__(16) unsigned short tile[64][72];
  {
    int tc = t & 63, tr = t >> 6;
    for (int p = 0; p < 16; ++p) {
      int row = tr + p * 4;
      int gi = g0 + row;
      float v = 0.f;
      if (gi < W) {
        float x;
        if constexpr (sizeof(TIN) == 4) x = X[(long long)gi * 64 + tc];
        else x = bf2f(X[(long long)gi * 64 + tc]);
        v = PRE ? fmaxf((x - mu) * rs, 0.f) : x;
      }
      tile[row][tc] = f2bf(v);
    }
  }
  __syncthreads();
  int oc = wave * 16 + (lane & 15);
  int g = lane >> 4;
  short8 b0 = *(const short8*)(Kb + oc * 64 + g * 8);
  short8 b1 = *(const short8*)(Kb + oc * 64 + 32 + g * 8);
  f32x4 acc[4] = {};
#pragma unroll
  for (int it = 0; it < 4; ++it) {
    short8 a0 = *(const short8*)(&tile[it * 16 + (lane & 15)][g * 8]);
    short8 a1 = *(const short8*)(&tile[it * 16 + (lane & 15)][32 + g * 8]);
    acc[it] = __builtin_amdgcn_mfma_f32_16x16x32_bf16(a0, b0, acc[it], 0, 0, 0);
    acc[it] = __builtin_amdgcn_mfma_f32_16x16x32_bf16(a1, b1, acc[it], 0, 0, 0);
  }
  float ssum = 0.f, ssq = 0.f;
  if constexpr (OUT_MODE == 2) {
    __shared__ float ot[64][65];
#pragma unroll
    for (int it = 0; it < 4; ++it)
#pragma unroll
      for (int rg = 0; rg < 4; ++rg)
        ot[it * 16 + 4 * g + rg][oc] = acc[it][rg];
    __syncthreads();
    int tc = t & 63, tr = t >> 6;
    for (int p = 0; p < 16; ++p) {
      int cc = tr + p * 4;
      int gi = g0 + tc;
      if (gi < W) Yf[(long long)cc * ldC + gi] = ot[tc][cc];
    }
  } else {
#pragma unroll
    for (int it = 0; it < 4; ++it) {
#pragma unroll
      for (int rg = 0; rg < 4; ++rg) {
        int row = it * 16 + 4 * g + rg;
        int gi = g0 + row;
        if (gi < W) {
          float v = acc[it][rg];
          if constexpr (STATS) { ssum += v; ssq += v * v; }
          long long idx = (long long)gi * 64 + oc;
          if constexpr (OUT_MODE == 0) Yb[idx] = f2bf(v);
          else if constexpr (OUT_MODE == 1) Yf[idx] += HSTEP * v;
          else Yf[idx] = v;
        }
      }
    }
  }
  if constexpr (STATS) stats_reduce(ssum, ssq, sOut);
}

// ---- edge feature build + K1E (64x192) ----
__global__ __launch_bounds__(256) void k_edgeA(
    const float* __restrict__ xnt, const float* __restrict__ xet,
    const int* __restrict__ iInd, const int* __restrict__ jInd,
    const unsigned short* __restrict__ Kb, unsigned short* __restrict__ Y,
    int E, double* __restrict__ sOut) {
  __shared__ __align__(16) unsigned short feat[64][200];
  int t = threadIdx.x;
  int wave = t >> 6, lane = t & 63;
  long long e0 = (long long)blockIdx.x * 64;
  int tc = t & 63, tr = t >> 6;
  for (int p = 0; p < 16; ++p) {
    int r = tr + p * 4;
    long long e = e0 + r;
    float xi = 0.f, xj = 0.f, xev = 0.f;
    if (e < E) {
      int vi = iInd[e], vj = jInd[e];
      xi = xnt[(long long)vi * 64 + tc];
      xj = xnt[(long long)vj * 64 + tc];
      xev = xet[e * 64 + tc];
    }
    feat[r][tc] = f2bf(0.5f * (xi + xj));
    feat[r][64 + tc] = f2bf(xev);
    feat[r][128 + tc] = f2bf(xi - xj);
  }
  __syncthreads();
  int oc = wave * 16 + (lane & 15);
  int g = lane >> 4;
  short8 bfr[6];
#pragma unroll
  for (int k = 0; k < 6; ++k) bfr[k] = *(const short8*)(Kb + oc * 192 + k * 32 + g * 8);
  f32x4 acc[4] = {};
#pragma unroll
  for (int it = 0; it < 4; ++it)
#pragma unroll
    for (int k = 0; k < 6; ++k) {
      short8 a = *(const short8*)(&feat[it * 16 + (lane & 15)][k * 32 + g * 8]);
      acc[it] = __builtin_amdgcn_mfma_f32_16x16x32_bf16(a, bfr[k], acc[it], 0, 0, 0);
    }
  float ssum = 0.f, ssq = 0.f;
#pragma unroll
  for (int it = 0; it < 4; ++it)
#pragma unroll
    for (int rg = 0; rg < 4; ++rg) {
      int row = it * 16 + 4 * g + rg;
      long long e = e0 + row;
      if (e < E) {
        float v = acc[it][rg];
        ssum += v; ssq += v * v;
        Y[e * 64 + oc] = f2bf(v);
      }
    }
  stats_reduce(ssum, ssq, sOut);
}

// ---- node feature build + KN1 (64x192) ----
__global__ __launch_bounds__(256) void k_nodeA(
    const float* __restrict__ si, const float* __restrict__ sj, const float* __restrict__ xnt,
    const unsigned short* __restrict__ Kb, unsigned short* __restrict__ Y,
    int N, double* __restrict__ sOut) {
  __shared__ __align__(16) unsigned short feat[64][200];
  int t = threadIdx.x;
  int wave = t >> 6, lane = t & 63;
  int n0 = blockIdx.x * 64;
  int tc = t & 63, tr = t >> 6;
  for (int p = 0; p < 16; ++p) {
    int r = tr + p * 4;
    int gi = n0 + r;
    float a = 0.f, b = 0.f, x = 0.f;
    if (gi < N) {
      long long base = (long long)gi * 64 + tc;
      a = si[base]; b = sj[base]; x = xnt[base];
    }
    feat[r][tc] = f2bf(0.5f * (a + b));
    feat[r][64 + tc] = f2bf(a - b);
    feat[r][128 + tc] = f2bf(x);
  }
  __syncthreads();
  int oc = wave * 16 + (lane & 15);
  int g = lane >> 4;
  short8 bfr[6];
#pragma unroll
  for (int k = 0; k < 6; ++k) bfr[k] = *(const short8*)(Kb + oc * 192 + k * 32 + g * 8);
  f32x4 acc[4] = {};
#pragma unroll
  for (int it = 0; it < 4; ++it)
#pragma unroll
    for (int k = 0; k < 6; ++k) {
      short8 a = *(const short8*)(&feat[it * 16 + (lane & 15)][k * 32 + g * 8]);
      acc[it] = __builtin_amdgcn_mfma_f32_16x16x32_bf16(a, bfr[k], acc[it], 0, 0, 0);
    }
  float ssum = 0.f, ssq = 0.f;
#pragma unroll
  for (int it = 0; it < 4; ++it)
#pragma unroll
    for (int rg = 0; rg < 4; ++rg) {
      int row = it * 16 + 4 * g + rg;
      int gi = n0 + row;
      if (gi < N) {
        float v = acc[it][rg];
        ssum += v; ssq += v * v;
        Y[(long long)gi * 64 + oc] = f2bf(v);
      }
    }
  stats_reduce(ssum, ssq, sOut);
}

// ---- dxe finalize + xe update + scatter old xe into si/sj ----
__global__ __launch_bounds__(256) void k_scatter(
    const unsigned short* __restrict__ t3, const double* __restrict__ sIn, long long cnt,
    float* __restrict__ xet, float* __restrict__ si, float* __restrict__ sj,
    const int* __restrict__ iInd, const int* __restrict__ jInd, long long E) {
  long long idx = (long long)blockIdx.x * 256 + threadIdx.x;
  if (idx >= E * 64) return;
  long long e = idx >> 6;
  int c = idx & 63;
  float mu, rs;
  ln_params(sIn, cnt, mu, rs);
  float dxe = (bf2f(t3[idx]) - mu) * rs;
  float old = xet[idx];
  xet[idx] = old + HSTEP * dxe;
  atomicAdd(si + (long long)iInd[e] * 64 + c, old);
  atomicAdd(sj + (long long)jInd[e] * 64 + c, old);
}

extern "C" void kernel_launch(void* const* d_in, const int* in_sizes, int n_in,
                              void* d_out, int out_size, void* d_ws, size_t ws_size,
                              hipStream_t stream) {
  (void)n_in; (void)out_size; (void)ws_size;
  const float* xn  = (const float*)d_in[0];
  const float* xe  = (const float*)d_in[1];
  const int* iInd  = (const int*)d_in[2];
  const int* jInd  = (const int*)d_in[3];
  const float* K1N = (const float*)d_in[4];
  const float* K2N = (const float*)d_in[5];
  const float* K1E = (const float*)d_in[6];
  const float* K2E = (const float*)d_in[7];
  const float* KNc = (const float*)d_in[8];
  const float* KE1 = (const float*)d_in[9];
  const float* KE2 = (const float*)d_in[10];
  const float* KN1 = (const float*)d_in[11];
  const float* KN2 = (const float*)d_in[12];
  int N = in_sizes[0] / 64;
  int E = in_sizes[2];
  float* out = (float*)d_out;

  size_t off = 0;
  auto carve = [&](size_t bytes) -> void* {
    void* p = (char*)d_ws + off;
    off += (bytes + 255) & ~(size_t)255;
    return p;
  };
  float* xnt = (float*)carve((size_t)N * 64 * 4);
  float* xet = (float*)carve((size_t)E * 64 * 4);
  unsigned short* t1e = (unsigned short*)carve((size_t)E * 64 * 2);
  unsigned short* t1n = (unsigned short*)carve((size_t)N * 64 * 2);
  float* si = (float*)carve((size_t)N * 64 * 4);
  float* sj = (float*)carve((size_t)N * 64 * 4);
  double* stats = (double*)carve(16 * sizeof(double));
  unsigned short* kw = (unsigned short*)carve(86016 * 2);

  unsigned short* kw_K1N = kw;
  unsigned short* kw_K2N = kw + 4096;
  unsigned short* kw_K1E = kw + 8192;
  unsigned short* kw_K2E = kw + 12288;
  unsigned short* kw_KNc = kw + 16384;
  unsigned short* kw_KE1 = kw + 20480;
  unsigned short* kw_KE2 = kw + 45056;
  unsigned short* kw_KN1 = kw + 53248;
  unsigned short* kw_KN2 = kw + 77824;

  hipMemsetAsync(stats, 0, 16 * sizeof(double), stream);
  k_cvt<<<16, 256, 0, stream>>>(K1N, kw_K1N, 4096);
  k_cvt<<<16, 256, 0, stream>>>(K2N, kw_K2N, 4096);
  k_cvt<<<16, 256, 0, stream>>>(K1E, kw_K1E, 4096);
  k_cvt<<<16, 256, 0, stream>>>(K2E, kw_K2E, 4096);
  k_cvt<<<16, 256, 0, stream>>>(KNc, kw_KNc, 4096);
  k_cvt<<<96, 256, 0, stream>>>(KE1, kw_KE1, 24576);
  k_cvt<<<32, 256, 0, stream>>>(KE2, kw_KE2, 8192);
  k_cvt<<<96, 256, 0, stream>>>(KN1, kw_KN1, 24576);
  k_cvt<<<32, 256, 0, stream>>>(KN2, kw_KN2, 8192);

  int gN = (N + 63) / 64, gE = (E + 63) / 64;
  long long cntN = 64LL * N, cntE = 64LL * E;
  k_transpose<<<dim3(gN, 1), 256, 0, stream>>>(xn, xnt, 64, N);
  k_transpose<<<dim3(gE, 1), 256, 0, stream>>>(xe, xet, 64, E);

  double* sON = stats + 0;
  double* sOE = stats + 2;
  k_mv64<0,1,0,float><<<gN,256,0,stream>>>(xnt, kw_K1N, t1n, nullptr, N, cntN, nullptr, sON, 0);
  k_mv64<1,0,3,unsigned short><<<gN,256,0,stream>>>(t1n, kw_K2N, nullptr, xnt, N, cntN, sON, nullptr, 0);
  k_mv64<0,1,0,float><<<gE,256,0,stream>>>(xet, kw_K1E, t1e, nullptr, E, cntE, nullptr, sOE, 0);
  k_mv64<1,0,3,unsigned short><<<gE,256,0,stream>>>(t1e, kw_K2E, nullptr, xet, E, cntE, sOE, nullptr, 0);

  for (int L = 0; L < 2; ++L) {
    double* sA = stats + 4 + L * 6;
    double* sB = sA + 2;
    double* sC = sA + 4;
    k_edgeA<<<gE,256,0,stream>>>(xnt, xet, iInd, jInd, kw_KE1 + L * 12288, t1e, E, sA);
    k_mv64<1,1,0,unsigned short><<<gE,256,0,stream>>>(t1e, kw_KE2 + L * 4096, t1e, nullptr, E, cntE, sA, sB, 0);
    hipMemsetAsync(si, 0, (size_t)N * 64 * 4, stream);
    hipMemsetAsync(sj, 0, (size_t)N * 64 * 4, stream);
    k_scatter<<<(int)(((long long)E * 64 + 255) / 256), 256, 0, stream>>>(
        t1e, sB, cntE, xet, si, sj, iInd, jInd, E);
    k_nodeA<<<gN,256,0,stream>>>(si, sj, xnt, kw_KN1 + L * 12288, t1n, N, sC);
    k_mv64<1,0,1,unsigned short><<<gN,256,0,stream>>>(t1n, kw_KN2 + L * 4096, nullptr, xnt, N, cntN, sC, nullptr, 0);
  }

  k_mv64<0,0,2,float><<<gN,256,0,stream>>>(xnt, kw_KNc, nullptr, out, N, cntN, nullptr, nullptr, N);
  k_transpose<<<dim3(1, gE), 256, 0, stream>>>(xet, out + (long long)64 * N, E, 64);
}

// Round 2
// 1301.679 us; speedup vs baseline: 1.1502x; 1.1502x over previous
//
#include <hip/hip_runtime.h>
#include <hip/hip_bf16.h>

#define HSTEP 0.1f
#define LN_EPS 1e-5f

typedef short short8 __attribute__((ext_vector_type(8)));
typedef float f32x4 __attribute__((ext_vector_type(4)));

__device__ __forceinline__ unsigned short f2bf(float f) {
  unsigned u = __builtin_bit_cast(unsigned, f);
  u += 0x7FFFu + ((u >> 16) & 1u);
  return (unsigned short)(u >> 16);
}
__device__ __forceinline__ float bf2f(unsigned short s) {
  unsigned u = ((unsigned)s) << 16;
  return __builtin_bit_cast(float, u);
}
__device__ __forceinline__ float bf2f_s(short s) { return bf2f((unsigned short)s); }

__device__ __forceinline__ void stats_reduce(float ssum, float ssq, double* sOut) {
  for (int off = 32; off; off >>= 1) {
    ssum += __shfl_down(ssum, off);
    ssq  += __shfl_down(ssq, off);
  }
  __shared__ float rs_[4], rq_[4];
  int t = threadIdx.x;
  if ((t & 63) == 0) { rs_[t >> 6] = ssum; rq_[t >> 6] = ssq; }
  __syncthreads();
  if (t == 0) {
    atomicAdd(sOut + 0, (double)(rs_[0] + rs_[1] + rs_[2] + rs_[3]));
    atomicAdd(sOut + 1, (double)(rq_[0] + rq_[1] + rq_[2] + rq_[3]));
  }
}

__device__ __forceinline__ void ln_params(const double* sIn, long long cnt, float& mu, float& rs) {
  float cf = (float)cnt;
  float m = (float)sIn[0] / cf;
  float q = (float)sIn[1] / cf;
  mu = m;
  rs = rsqrtf(fmaxf(q - m * m, 0.f) + LN_EPS);
}

// ---- all weights fp32 -> bf16, one launch ----
__global__ __launch_bounds__(256) void k_cvt_all(
    const float* __restrict__ K1N, const float* __restrict__ K2N,
    const float* __restrict__ K1E, const float* __restrict__ K2E,
    const float* __restrict__ KNc, const float* __restrict__ KE1,
    const float* __restrict__ KE2, const float* __restrict__ KN1,
    const float* __restrict__ KN2, unsigned short* __restrict__ kw) {
  int i = blockIdx.x * 256 + threadIdx.x;
  if (i >= 86016) return;
  const float* s; int off;
  if (i < 4096)       { s = K1N; off = 0; }
  else if (i < 8192)  { s = K2N; off = 4096; }
  else if (i < 12288) { s = K1E; off = 8192; }
  else if (i < 16384) { s = K2E; off = 12288; }
  else if (i < 20480) { s = KNc; off = 16384; }
  else if (i < 45056) { s = KE1; off = 20480; }
  else if (i < 53248) { s = KE2; off = 45056; }
  else if (i < 77824) { s = KN1; off = 53248; }
  else                { s = KN2; off = 77824; }
  kw[i] = f2bf(s[i - off]);
}

// ---- fused: read X channel-major fp32 (64 x W), Y = K1 @ X -> bf16 row-major + stats ----
__global__ __launch_bounds__(256) void k_open(
    const float* __restrict__ X, const unsigned short* __restrict__ Kb,
    unsigned short* __restrict__ Y, int W, double* __restrict__ sOut) {
  __shared__ __align__(16) unsigned short tile[64][72];
  int t = threadIdx.x;
  int wave = t >> 6, lane = t & 63;
  int g0 = blockIdx.x * 64;
  int tc = t & 63, tr = t >> 6;
#pragma unroll
  for (int p = 0; p < 16; ++p) {
    int c = tr + p * 4;
    int item = g0 + tc;
    float v = (item < W) ? X[(long long)c * W + item] : 0.f;
    tile[tc][c] = f2bf(v);
  }
  __syncthreads();
  int oc = wave * 16 + (lane & 15);
  int g = lane >> 4;
  short8 b0 = *(const short8*)(Kb + oc * 64 + g * 8);
  short8 b1 = *(const short8*)(Kb + oc * 64 + 32 + g * 8);
  f32x4 acc[4] = {};
#pragma unroll
  for (int it = 0; it < 4; ++it) {
    short8 a0 = *(const short8*)(&tile[it * 16 + (lane & 15)][g * 8]);
    short8 a1 = *(const short8*)(&tile[it * 16 + (lane & 15)][32 + g * 8]);
    acc[it] = __builtin_amdgcn_mfma_f32_16x16x32_bf16(a0, b0, acc[it], 0, 0, 0);
    acc[it] = __builtin_amdgcn_mfma_f32_16x16x32_bf16(a1, b1, acc[it], 0, 0, 0);
  }
  float ssum = 0.f, ssq = 0.f;
  __syncthreads();
#pragma unroll
  for (int it = 0; it < 4; ++it)
#pragma unroll
    for (int rg = 0; rg < 4; ++rg) {
      int row = it * 16 + 4 * g + rg;
      float v = acc[it][rg];
      if (g0 + row < W) { ssum += v; ssq += v * v; }
      tile[row][oc] = f2bf(v);
    }
  __syncthreads();
  int r = t >> 2, q = t & 3;
  int gi = g0 + r;
  if (gi < W) {
    *(short8*)(Y + (long long)gi * 64 + q * 16) = *(const short8*)&tile[r][q * 16];
    *(short8*)(Y + (long long)gi * 64 + q * 16 + 8) = *(const short8*)&tile[r][q * 16 + 8];
  }
  stats_reduce(ssum, ssq, sOut);
}

// ---- generic 64x64 apply on bf16 row-major X ----
// PRE: 0 none, 1 relu(ln(x)) ; OUT_MODE: 0 bf16 row-major, 1 bf16 += H*acc, 2 fp32 channel-major (ldC)
template<int PRE, int STATS, int OUT_MODE>
__global__ __launch_bounds__(256) void k_mv64(
    const unsigned short* __restrict__ X, const unsigned short* __restrict__ Kb,
    unsigned short* __restrict__ Yb, float* __restrict__ Yf,
    int W, long long cnt, const double* __restrict__ sIn, double* __restrict__ sOut, int ldC) {
  int t = threadIdx.x;
  int wave = t >> 6, lane = t & 63;
  int g0 = blockIdx.x * 64;
  float mu = 0.f, rsg = 1.f;
  if constexpr (PRE) ln_params(sIn, cnt, mu, rsg);
  __shared__ __align__(16) unsigned short tile[64][72];
  int r = t >> 2, q = t & 3;
  {
    int gi = g0 + r;
    short8 v0 = {}, v1 = {};
    if (gi < W) {
      const unsigned short* px = X + (long long)gi * 64 + q * 16;
      v0 = *(const short8*)px;
      v1 = *(const short8*)(px + 8);
    }
    if constexpr (PRE) {
#pragma unroll
      for (int c = 0; c < 8; ++c) {
        v0[c] = (short)f2bf(fmaxf((bf2f_s(v0[c]) - mu) * rsg, 0.f));
        v1[c] = (short)f2bf(fmaxf((bf2f_s(v1[c]) - mu) * rsg, 0.f));
      }
    }
    *(short8*)&tile[r][q * 16] = v0;
    *(short8*)&tile[r][q * 16 + 8] = v1;
  }
  __syncthreads();
  int oc = wave * 16 + (lane & 15);
  int g = lane >> 4;
  short8 b0 = *(const short8*)(Kb + oc * 64 + g * 8);
  short8 b1 = *(const short8*)(Kb + oc * 64 + 32 + g * 8);
  f32x4 acc[4] = {};
#pragma unroll
  for (int it = 0; it < 4; ++it) {
    short8 a0 = *(const short8*)(&tile[it * 16 + (lane & 15)][g * 8]);
    short8 a1 = *(const short8*)(&tile[it * 16 + (lane & 15)][32 + g * 8]);
    acc[it] = __builtin_amdgcn_mfma_f32_16x16x32_bf16(a0, b0, acc[it], 0, 0, 0);
    acc[it] = __builtin_amdgcn_mfma_f32_16x16x32_bf16(a1, b1, acc[it], 0, 0, 0);
  }
  float ssum = 0.f, ssq = 0.f;
  if constexpr (OUT_MODE == 0) {
    __syncthreads();
#pragma unroll
    for (int it = 0; it < 4; ++it)
#pragma unroll
      for (int rg = 0; rg < 4; ++rg) {
        int row = it * 16 + 4 * g + rg;
        float v = acc[it][rg];
        if constexpr (STATS) { if (g0 + row < W) { ssum += v; ssq += v * v; } }
        tile[row][oc] = f2bf(v);
      }
    __syncthreads();
    int gi = g0 + r;
    if (gi < W) {
      *(short8*)(Yb + (long long)gi * 64 + q * 16) = *(const short8*)&tile[r][q * 16];
      *(short8*)(Yb + (long long)gi * 64 + q * 16 + 8) = *(const short8*)&tile[r][q * 16 + 8];
    }
  } else if constexpr (OUT_MODE == 1) {
#pragma unroll
    for (int it = 0; it < 4; ++it)
#pragma unroll
      for (int rg = 0; rg < 4; ++rg) {
        int row = it * 16 + 4 * g + rg;
        int gi = g0 + row;
        if (gi < W) {
          long long idx = (long long)gi * 64 + oc;
          Yb[idx] = f2bf(bf2f(Yb[idx]) + HSTEP * acc[it][rg]);
        }
      }
  } else {
    __shared__ float ot[64][65];
#pragma unroll
    for (int it = 0; it < 4; ++it)
#pragma unroll
      for (int rg = 0; rg < 4; ++rg)
        ot[it * 16 + 4 * g + rg][oc] = acc[it][rg];
    __syncthreads();
    int tc2 = t & 63, tr2 = t >> 6;
    for (int p = 0; p < 16; ++p) {
      int cc = tr2 + p * 4;
      int gi = g0 + tc2;
      if (gi < W) Yf[(long long)cc * ldC + gi] = ot[tc2][cc];
    }
  }
  if constexpr (STATS) stats_reduce(ssum, ssq, sOut);
}

// ---- edge feature build (bf16 gather) + K1E (64x192) ----
__global__ __launch_bounds__(256) void k_edgeA(
    const unsigned short* __restrict__ xnt, const unsigned short* __restrict__ xet,
    const int* __restrict__ iInd, const int* __restrict__ jInd,
    const unsigned short* __restrict__ Kb, unsigned short* __restrict__ Y,
    long long E, double* __restrict__ sOut) {
  __shared__ int inds[128];
  __shared__ __align__(16) unsigned short feat[64][200];
  int t = threadIdx.x;
  int wave = t >> 6, lane = t & 63;
  long long e0 = (long long)blockIdx.x * 64;
  if (t < 64) inds[t] = (e0 + t < E) ? iInd[e0 + t] : 0;
  else if (t < 128) inds[t] = (e0 + t - 64 < E) ? jInd[e0 + t - 64] : 0;
  __syncthreads();
  int r = t >> 2, q = t & 3;
  long long e = e0 + r;
  short8 xi0 = {}, xi1 = {}, xj0 = {}, xj1 = {}, xe0 = {}, xe1 = {};
  if (e < E) {
    long long vi = inds[r], vj = inds[64 + r];
    const unsigned short* pi = xnt + vi * 64 + q * 16;
    const unsigned short* pj = xnt + vj * 64 + q * 16;
    const unsigned short* pe = xet + e * 64 + q * 16;
    xi0 = *(const short8*)pi; xi1 = *(const short8*)(pi + 8);
    xj0 = *(const short8*)pj; xj1 = *(const short8*)(pj + 8);
    xe0 = *(const short8*)pe; xe1 = *(const short8*)(pe + 8);
  }
  short8 i0, i1, gg0, gg1;
#pragma unroll
  for (int c = 0; c < 8; ++c) {
    float a0 = bf2f_s(xi0[c]), b0v = bf2f_s(xj0[c]);
    float a1 = bf2f_s(xi1[c]), b1v = bf2f_s(xj1[c]);
    i0[c]  = (short)f2bf(0.5f * (a0 + b0v));
    i1[c]  = (short)f2bf(0.5f * (a1 + b1v));
    gg0[c] = (short)f2bf(a0 - b0v);
    gg1[c] = (short)f2bf(a1 - b1v);
  }
  *(short8*)&feat[r][q * 16]           = i0;
  *(short8*)&feat[r][q * 16 + 8]       = i1;
  *(short8*)&feat[r][64 + q * 16]      = xe0;
  *(short8*)&feat[r][64 + q * 16 + 8]  = xe1;
  *(short8*)&feat[r][128 + q * 16]     = gg0;
  *(short8*)&feat[r][128 + q * 16 + 8] = gg1;
  __syncthreads();
  int oc = wave * 16 + (lane & 15);
  int g = lane >> 4;
  short8 bfr[6];
#pragma unroll
  for (int k = 0; k < 6; ++k) bfr[k] = *(const short8*)(Kb + oc * 192 + k * 32 + g * 8);
  f32x4 acc[4] = {};
#pragma unroll
  for (int it = 0; it < 4; ++it)
#pragma unroll
    for (int k = 0; k < 6; ++k) {
      short8 a = *(const short8*)(&feat[it * 16 + (lane & 15)][k * 32 + g * 8]);
      acc[it] = __builtin_amdgcn_mfma_f32_16x16x32_bf16(a, bfr[k], acc[it], 0, 0, 0);
    }
  float ssum = 0.f, ssq = 0.f;
  __syncthreads();
#pragma unroll
  for (int it = 0; it < 4; ++it)
#pragma unroll
    for (int rg = 0; rg < 4; ++rg) {
      int row = it * 16 + 4 * g + rg;
      float v = acc[it][rg];
      if (e0 + row < E) { ssum += v; ssq += v * v; }
      feat[row][oc] = f2bf(v);
    }
  __syncthreads();
  if (e < E) {
    *(short8*)(Y + e * 64 + q * 16)     = *(const short8*)&feat[r][q * 16];
    *(short8*)(Y + e * 64 + q * 16 + 8) = *(const short8*)&feat[r][q * 16 + 8];
  }
  stats_reduce(ssum, ssq, sOut);
}

// ---- node feature build + KN1 (64x192) ----
__global__ __launch_bounds__(256) void k_nodeA(
    const float* __restrict__ si, const float* __restrict__ sj,
    const unsigned short* __restrict__ xnt,
    const unsigned short* __restrict__ Kb, unsigned short* __restrict__ Y,
    int N, double* __restrict__ sOut) {
  __shared__ __align__(16) unsigned short feat[64][200];
  int t = threadIdx.x;
  int wave = t >> 6, lane = t & 63;
  int n0b = blockIdx.x * 64;
  int r = t >> 2, q = t & 3;
  int n = n0b + r;
  f32x4 a[4] = {}, b[4] = {};
  short8 x0 = {}, x1 = {};
  if (n < N) {
    const float* ps = si + (long long)n * 64 + q * 16;
    const float* pj = sj + (long long)n * 64 + q * 16;
#pragma unroll
    for (int k = 0; k < 4; ++k) {
      a[k] = *(const f32x4*)(ps + 4 * k);
      b[k] = *(const f32x4*)(pj + 4 * k);
    }
    const unsigned short* px = xnt + (long long)n * 64 + q * 16;
    x0 = *(const short8*)px; x1 = *(const short8*)(px + 8);
  }
  short8 av0, av1, dv0, dv1;
#pragma unroll
  for (int c = 0; c < 8; ++c) {
    float sa = a[c >> 2][c & 3], sb = b[c >> 2][c & 3];
    av0[c] = (short)f2bf(0.5f * (sa + sb));
    dv0[c] = (short)f2bf(sa - sb);
    float sa1 = a[2 + (c >> 2)][c & 3], sb1 = b[2 + (c >> 2)][c & 3];
    av1[c] = (short)f2bf(0.5f * (sa1 + sb1));
    dv1[c] = (short)f2bf(sa1 - sb1);
  }
  *(short8*)&feat[r][q * 16]           = av0;
  *(short8*)&feat[r][q * 16 + 8]       = av1;
  *(short8*)&feat[r][64 + q * 16]      = dv0;
  *(short8*)&feat[r][64 + q * 16 + 8]  = dv1;
  *(short8*)&feat[r][128 + q * 16]     = x0;
  *(short8*)&feat[r][128 + q * 16 + 8] = x1;
  __syncthreads();
  int oc = wave * 16 + (lane & 15);
  int g = lane >> 4;
  short8 bfr[6];
#pragma unroll
  for (int k = 0; k < 6; ++k) bfr[k] = *(const short8*)(Kb + oc * 192 + k * 32 + g * 8);
  f32x4 acc[4] = {};
#pragma unroll
  for (int it = 0; it < 4; ++it)
#pragma unroll
    for (int k = 0; k < 6; ++k) {
      short8 av = *(const short8*)(&feat[it * 16 + (lane & 15)][k * 32 + g * 8]);
      acc[it] = __builtin_amdgcn_mfma_f32_16x16x32_bf16(av, bfr[k], acc[it], 0, 0, 0);
    }
  float ssum = 0.f, ssq = 0.f;
  __syncthreads();
#pragma unroll
  for (int it = 0; it < 4; ++it)
#pragma unroll
    for (int rg = 0; rg < 4; ++rg) {
      int row = it * 16 + 4 * g + rg;
      float v = acc[it][rg];
      if (n0b + row < N) { ssum += v; ssq += v * v; }
      feat[row][oc] = f2bf(v);
    }
  __syncthreads();
  if (n < N) {
    *(short8*)(Y + (long long)n * 64 + q * 16)     = *(const short8*)&feat[r][q * 16];
    *(short8*)(Y + (long long)n * 64 + q * 16 + 8) = *(const short8*)&feat[r][q * 16 + 8];
  }
  stats_reduce(ssum, ssq, sOut);
}

// ---- dxe finalize + xe update + scatter old xe; WOUT=1 also writes out1 channel-major ----
template<int WOUT>
__global__ __launch_bounds__(256) void k_scatter(
    const unsigned short* __restrict__ t3, const double* __restrict__ sIn, long long cnt,
    unsigned short* __restrict__ xet, float* __restrict__ si, float* __restrict__ sj,
    const int* __restrict__ iInd, const int* __restrict__ jInd, long long E,
    float* __restrict__ out1) {
  __shared__ int inds[128];
  __shared__ __align__(16) unsigned short told[64][72];
  __shared__ float tnew[WOUT ? 64 : 1][65];
  int t = threadIdx.x;
  long long e0 = (long long)blockIdx.x * 64;
  if (t < 64) inds[t] = (e0 + t < E) ? iInd[e0 + t] : 0;
  else if (t < 128) inds[t] = (e0 + t - 64 < E) ? jInd[e0 + t - 64] : 0;
  float mu, rsg;
  ln_params(sIn, cnt, mu, rsg);
  int r = t >> 2, q = t & 3;
  long long e = e0 + r;
  short8 o0 = {}, o1 = {}, z0 = {}, z1 = {};
  if (e < E) {
    const unsigned short* po = xet + e * 64 + q * 16;
    const unsigned short* pz = t3 + e * 64 + q * 16;
    o0 = *(const short8*)po; o1 = *(const short8*)(po + 8);
    z0 = *(const short8*)pz; z1 = *(const short8*)(pz + 8);
  }
  short8 n0v, n1v;
#pragma unroll
  for (int c = 0; c < 8; ++c) {
    float new0 = bf2f_s(o0[c]) + HSTEP * ((bf2f_s(z0[c]) - mu) * rsg);
    float new1 = bf2f_s(o1[c]) + HSTEP * ((bf2f_s(z1[c]) - mu) * rsg);
    n0v[c] = (short)f2bf(new0);
    n1v[c] = (short)f2bf(new1);
    if constexpr (WOUT) {
      tnew[r][q * 16 + c] = new0;
      tnew[r][q * 16 + 8 + c] = new1;
    }
  }
  *(short8*)&told[r][q * 16]     = o0;
  *(short8*)&told[r][q * 16 + 8] = o1;
  if (e < E) {
    unsigned short* po = xet + e * 64 + q * 16;
    *(short8*)po = n0v;
    *(short8*)(po + 8) = n1v;
  }
  __syncthreads();
  int tc = t & 63, tr = t >> 6;
  for (int p = 0; p < 16; ++p) {
    int rr = tr + p * 4;
    long long ee = e0 + rr;
    if (ee < E) {
      float old = bf2f(told[rr][tc]);
      atomicAdd(si + (long long)inds[rr] * 64 + tc, old);
      atomicAdd(sj + (long long)inds[64 + rr] * 64 + tc, old);
    }
  }
  if constexpr (WOUT) {
    long long ee = e0 + tc;
#pragma unroll
    for (int p = 0; p < 16; ++p) {
      int cc = tr + p * 4;
      if (ee < E) out1[(long long)cc * E + ee] = tnew[tc][cc];
    }
  }
}

extern "C" void kernel_launch(void* const* d_in, const int* in_sizes, int n_in,
                              void* d_out, int out_size, void* d_ws, size_t ws_size,
                              hipStream_t stream) {
  (void)n_in; (void)out_size; (void)ws_size;
  const float* xn  = (const float*)d_in[0];
  const float* xe  = (const float*)d_in[1];
  const int* iInd  = (const int*)d_in[2];
  const int* jInd  = (const int*)d_in[3];
  const float* K1N = (const float*)d_in[4];
  const float* K2N = (const float*)d_in[5];
  const float* K1E = (const float*)d_in[6];
  const float* K2E = (const float*)d_in[7];
  const float* KNc = (const float*)d_in[8];
  const float* KE1 = (const float*)d_in[9];
  const float* KE2 = (const float*)d_in[10];
  const float* KN1 = (const float*)d_in[11];
  const float* KN2 = (const float*)d_in[12];
  int N = in_sizes[0] / 64;
  long long E = in_sizes[2];
  float* out = (float*)d_out;

  size_t off = 0;
  auto carve = [&](size_t bytes) -> void* {
    void* p = (char*)d_ws + off;
    off += (bytes + 255) & ~(size_t)255;
    return p;
  };
  unsigned short* xnt = (unsigned short*)carve((size_t)N * 64 * 2);
  unsigned short* xet = (unsigned short*)carve((size_t)E * 64 * 2);
  unsigned short* t1e = (unsigned short*)carve((size_t)E * 64 * 2);
  unsigned short* t1n = (unsigned short*)carve((size_t)N * 64 * 2);
  float* si = (float*)carve((size_t)N * 64 * 4);
  float* sj = (float*)carve((size_t)N * 64 * 4);
  double* stats = (double*)carve(16 * sizeof(double));
  unsigned short* kw = (unsigned short*)carve(86016 * 2);

  unsigned short* kw_K1N = kw;
  unsigned short* kw_K2N = kw + 4096;
  unsigned short* kw_K1E = kw + 8192;
  unsigned short* kw_K2E = kw + 12288;
  unsigned short* kw_KNc = kw + 16384;
  unsigned short* kw_KE1 = kw + 20480;
  unsigned short* kw_KE2 = kw + 45056;
  unsigned short* kw_KN1 = kw + 53248;
  unsigned short* kw_KN2 = kw + 77824;

  hipMemsetAsync(stats, 0, 16 * sizeof(double), stream);
  k_cvt_all<<<336, 256, 0, stream>>>(K1N, K2N, K1E, K2E, KNc, KE1, KE2, KN1, KN2, kw);

  int gN = (N + 63) / 64;
  int gE = (int)((E + 63) / 64);
  long long cntN = 64LL * N, cntE = 64LL * E;
  double* sON = stats + 0;
  double* sOE = stats + 2;

  k_open<<<gN, 256, 0, stream>>>(xn, kw_K1N, t1n, N, sON);
  k_open<<<gE, 256, 0, stream>>>(xe, kw_K1E, t1e, (int)E, sOE);
  k_mv64<1,0,0><<<gN, 256, 0, stream>>>(t1n, kw_K2N, xnt, nullptr, N, cntN, sON, nullptr, 0);
  k_mv64<1,0,0><<<gE, 256, 0, stream>>>(t1e, kw_K2E, xet, nullptr, (int)E, cntE, sOE, nullptr, 0);

  float* out1 = out + (long long)64 * N;
  for (int L = 0; L < 2; ++L) {
    double* sA = stats + 4 + L * 6;
    double* sB = sA + 2;
    double* sC = sA + 4;
    k_edgeA<<<gE, 256, 0, stream>>>(xnt, xet, iInd, jInd, kw_KE1 + L * 12288, t1e, E, sA);
    k_mv64<1,1,0><<<gE, 256, 0, stream>>>(t1e, kw_KE2 + L * 4096, t1e, nullptr, (int)E, cntE, sA, sB, 0);
    hipMemsetAsync(si, 0, (size_t)N * 64 * 4, stream);
    hipMemsetAsync(sj, 0, (size_t)N * 64 * 4, stream);
    if (L == 0)
      k_scatter<0><<<gE, 256, 0, stream>>>(t1e, sB, cntE, xet, si, sj, iInd, jInd, E, nullptr);
    else
      k_scatter<1><<<gE, 256, 0, stream>>>(t1e, sB, cntE, xet, si, sj, iInd, jInd, E, out1);
    k_nodeA<<<gN, 256, 0, stream>>>(si, sj, xnt, kw_KN1 + L * 12288, t1n, N, sC);
    k_mv64<1,0,1><<<gN, 256, 0, stream>>>(t1n, kw_KN2 + L * 4096, xnt, nullptr, N, cntN, sC, nullptr, 0);
  }

  k_mv64<0,0,2><<<gN, 256, 0, stream>>>(xnt, kw_KNc, nullptr, out, N, cntN, nullptr, nullptr, N);
}